// Round 4
// baseline (427.426 us; speedup 1.0000x reference)
//
#include <hip/hip_runtime.h>
#include <hip/hip_bf16.h>
#include <stdint.h>

// BitNet-style quantized FFN for MI355X (gfx950).
// Pipeline: absmax(w1,w2) -> scales -> wquant -> LN+actquant ->
//           i8 GEMM1 (+dequant+bias+swish, bf16 out) -> actquant(h) ->
//           i8 GEMM2 (+dequant+bias+mask+residual, fp32 out)
// R8: faithful i8 port of the verified 256^2 8-phase schedule (m201/T3+T4+T5).
//     R4/R6/R7 all coarse-2-phase -> 19-24% MfmaUtil == m233's 25%-of-peak
//     2-phase ceiling (stage+vmcnt+barrier overhead is structural).
//     Here: 512 thr = 8 waves (2M x 4N), wave tile 128x64 = 4x2 frags of
//     32x32x32 i8 (acc 128 VGPR, 2 waves/SIMD); dbuf LDS 128KB (buf0=even
//     K-tiles, buf1=odd); iter = 2 K-tiles = 8 phases of {JIT ds_read of one
//     quadrant | 4 gload_lds of one half-tile | s_barrier | setprio(1)
//     8 MFMA setprio(0) | s_barrier}. Stage windows (ph0/3/4/7) start only
//     after the target half's last ds_read phase (B fully read by ph1,
//     A-half0 by ph2). Counted vmcnt(4) at end of ph3/ph7 only -- youngest
//     waited load is >=3 phases (~1700cy) old; never drains fresh loads.
// NB: SQ_LDS_BANK_CONFLICT == 8 cyc x staging-instr count (artifact of
//     global_load_lds write occupancy), not read conflicts.

typedef int v4i __attribute__((ext_vector_type(4)));
typedef int v16i __attribute__((ext_vector_type(16)));

__device__ __forceinline__ float wave_max64(float v) {
#pragma unroll
  for (int off = 32; off; off >>= 1) v = fmaxf(v, __shfl_xor(v, off, 64));
  return v;
}

__device__ __forceinline__ void load16_to_lds(const int8_t* g, int8_t* l) {
  __builtin_amdgcn_global_load_lds((const __attribute__((address_space(1))) void*)g,
                                   (__attribute__((address_space(3))) void*)l, 16, 0, 0);
}

// ---------------- per-tensor weight absmax ----------------
__global__ __launch_bounds__(256) void absmax_kernel(const float* __restrict__ w, int n4,
                                                     int* __restrict__ slot) {
  float m = 0.f;
  const float4* w4 = (const float4*)w;
  for (int i = blockIdx.x * 256 + threadIdx.x; i < n4; i += gridDim.x * 256) {
    float4 v = w4[i];
    m = fmaxf(fmaxf(fabsf(v.x), fabsf(v.y)), fmaxf(fmaxf(fabsf(v.z), fabsf(v.w)), m));
  }
  m = wave_max64(m);
  __shared__ float sm[4];
  int lane = threadIdx.x & 63, wv = threadIdx.x >> 6;
  if (!lane) sm[wv] = m;
  __syncthreads();
  if (!threadIdx.x) {
    m = fmaxf(fmaxf(sm[0], sm[1]), fmaxf(sm[2], sm[3]));
    atomicMax(slot, __float_as_int(m));  // nonneg float bits are int-monotone
  }
}

// ---------------- scales ----------------
__global__ void scales_kernel(const int* __restrict__ wmax, const int* __restrict__ bits,
                              float* __restrict__ scal) {
  float qb = (float)((1 << (bits[0] - 1)) - 1);
  scal[2] = qb / fmaxf(__int_as_float(wmax[0]), 1e-5f);
  scal[3] = qb / fmaxf(__int_as_float(wmax[1]), 1e-5f);
  scal[4] = qb;
}

// ---------------- weight quantization to int8 ----------------
__global__ __launch_bounds__(256) void wquant_kernel(const float* __restrict__ w,
                                                     const float* __restrict__ scal, int which,
                                                     int8_t* __restrict__ out) {
  float s = scal[2 + which], qb = scal[4];
  int i = blockIdx.x * 256 + threadIdx.x;
  float4 v = ((const float4*)w)[i];
  char4 q;
  q.x = (char)(int)rintf(fminf(fmaxf(v.x * s, -qb), qb));
  q.y = (char)(int)rintf(fminf(fmaxf(v.y * s, -qb), qb));
  q.z = (char)(int)rintf(fminf(fmaxf(v.z * s, -qb), qb));
  q.w = (char)(int)rintf(fminf(fmaxf(v.w * s, -qb), qb));
  ((char4*)out)[i] = q;
}

// ---------------- fused LayerNorm + per-row int8 absmax quant ----------------
__global__ __launch_bounds__(256) void ln_quant_kernel(const float* __restrict__ x,
                                                       const float* __restrict__ gamma,
                                                       const float* __restrict__ beta,
                                                       int8_t* __restrict__ xq,
                                                       float* __restrict__ xscale) {
  const int row = blockIdx.x;            // 16384 rows, D=1024
  const int tid = threadIdx.x;           // 256 threads x 4 elems
  const float4 v = ((const float4*)(x + (size_t)row * 1024))[tid];
  float s = v.x + v.y + v.z + v.w;
  float ss = fmaf(v.x, v.x, fmaf(v.y, v.y, fmaf(v.z, v.z, v.w * v.w)));
#pragma unroll
  for (int off = 32; off; off >>= 1) {
    s += __shfl_xor(s, off, 64);
    ss += __shfl_xor(ss, off, 64);
  }
  __shared__ float sm[8];
  const int lane = tid & 63, wv = tid >> 6;
  if (!lane) { sm[wv] = s; sm[4 + wv] = ss; }
  __syncthreads();
  s = sm[0] + sm[1] + sm[2] + sm[3];
  ss = sm[4] + sm[5] + sm[6] + sm[7];
  const float mu = s * (1.f / 1024.f);
  const float var = ss * (1.f / 1024.f) - mu * mu;
  const float rstd = rsqrtf(var + 1e-5f);
  const float4 g = ((const float4*)gamma)[tid];
  const float4 bb = ((const float4*)beta)[tid];
  float y0 = (v.x - mu) * rstd * g.x + bb.x;
  float y1 = (v.y - mu) * rstd * g.y + bb.y;
  float y2 = (v.z - mu) * rstd * g.z + bb.z;
  float y3 = (v.w - mu) * rstd * g.w + bb.w;
  float am = fmaxf(fmaxf(fabsf(y0), fabsf(y1)), fmaxf(fabsf(y2), fabsf(y3)));
  am = wave_max64(am);
  __syncthreads();
  if (!lane) sm[wv] = am;
  __syncthreads();
  am = fmaxf(fmaxf(sm[0], sm[1]), fmaxf(sm[2], sm[3]));
  const float scale = 127.f / fmaxf(am, 1e-5f);
  char4 q;
  q.x = (char)(int)rintf(fminf(fmaxf(y0 * scale, -127.f), 127.f));
  q.y = (char)(int)rintf(fminf(fmaxf(y1 * scale, -127.f), 127.f));
  q.z = (char)(int)rintf(fminf(fmaxf(y2 * scale, -127.f), 127.f));
  q.w = (char)(int)rintf(fminf(fmaxf(y3 * scale, -127.f), 127.f));
  ((char4*)(xq + (size_t)row * 1024))[tid] = q;
  if (!tid) xscale[row] = scale;
}

// ---------------- per-row int8 absmax quant of bf16 h [16384,4096] ----------------
__global__ __launch_bounds__(256) void hquant_kernel(const ushort* __restrict__ h,
                                                     int8_t* __restrict__ hq,
                                                     float* __restrict__ hscale) {
  const int row = blockIdx.x;
  const int tid = threadIdx.x;           // 256 threads x 16 elems
  const int4* p = (const int4*)(h + (size_t)row * 4096);
  union { int4 i4; ushort u[8]; } ua, ub;
  ua.i4 = p[tid * 2];
  ub.i4 = p[tid * 2 + 1];
  float f[16];
#pragma unroll
  for (int i = 0; i < 8; ++i) f[i] = __uint_as_float((unsigned)ua.u[i] << 16);
#pragma unroll
  for (int i = 0; i < 8; ++i) f[8 + i] = __uint_as_float((unsigned)ub.u[i] << 16);
  float am = 0.f;
#pragma unroll
  for (int i = 0; i < 16; ++i) am = fmaxf(am, fabsf(f[i]));
  am = wave_max64(am);
  __shared__ float sm[4];
  const int lane = tid & 63, wv = tid >> 6;
  if (!lane) sm[wv] = am;
  __syncthreads();
  am = fmaxf(fmaxf(sm[0], sm[1]), fmaxf(sm[2], sm[3]));
  const float scale = 127.f / fmaxf(am, 1e-5f);
  union { int4 i4; char c[16]; } q;
#pragma unroll
  for (int i = 0; i < 16; ++i)
    q.c[i] = (char)(int)rintf(fminf(fmaxf(f[i] * scale, -127.f), 127.f));
  ((int4*)(hq + (size_t)row * 4096))[tid] = q.i4;
  if (!tid) hscale[row] = scale;
}

// ---------------- i8 MFMA GEMM core (R8): 256x256, 8-phase, dbuf ----------------
// LDS layout per buffer: A[256][128] at +0, B[256][128] at +32768; 128-B rows,
// 16B-chunk c of row r at phys slot c^(r&7) (swizzle on global source addr;
// gload_lds dest linear; inverted on ds_read). buf0 = even K-tiles (smem+0),
// buf1 = odd (smem+65536). Iter it computes tiles t0=2it (ph0-3) and t1=2it+1
// (ph4-7), one wave-quadrant (2 m-frags x 1 n-frag x 4 ksteps = 8 MFMA) per
// phase. Stage windows: ph0: t1 half1 (always; completes prologue/ph7 start),
// ph3: t0+2 half0, ph4: t0+2 half1, ph7: t1+2 half0. vmcnt(4) end-ph3/ph7.
template <int K>
__device__ __forceinline__ void gemm_core_r8(const int8_t* __restrict__ A,
                                             const int8_t* __restrict__ B, int8_t* smem,
                                             v16i (&acc)[4][2], int mIdx, int nIdx) {
  constexpr int NI = K / 256;          // iterations (2 K-tiles each)
  const int tid = threadIdx.x;         // 512
  const int lane = tid & 63;
  const int wave = tid >> 6;           // 8 waves: 2M x 4N
  const int wm = (wave & 1) * 128;
  const int wn = (wave >> 1) * 64;
  const int lrow = lane & 31;
  const int half = lane >> 5;
  const int x7 = lrow & 7;
  const size_t m0 = (size_t)mIdx * 256;
  const size_t n0 = (size_t)nIdx * 256;

  // staging: 512 threads cover 64 rows x 8 chunks (8KB) per instr;
  // row r0=tid>>3, phys chunk tid&7 holds logical chunk (tid&7)^(r0&7)
  const int r0 = tid >> 3;
  const int c0 = ((tid & 7) ^ (r0 & 7)) << 4;
  const int8_t* ga = A + (m0 + r0) * K + c0;
  const int8_t* gb = B + (n0 + r0) * K + c0;
  int8_t* const lds0 = smem;
  int8_t* const lds1 = smem + 65536;

  // stage one half of a K-tile (rows h*128..h*128+127 of A and B; 4 instrs)
  auto stgHalf = [&](size_t ko, int8_t* lb, int h) {
    const int s0 = h * 2;
#pragma unroll
    for (int s = s0; s < s0 + 2; ++s) {
      load16_to_lds(ga + (size_t)(s * 64) * K + ko, lb + s * 8192 + tid * 16);
      load16_to_lds(gb + (size_t)(s * 64) * K + ko, lb + 32768 + s * 8192 + tid * 16);
    }
  };

  auto rdA = [&](const int8_t* lb, int i, int ks) {
    return *(const v4i*)(lb + (wm + i * 32 + lrow) * 128 + (((ks * 2 + half) ^ x7) << 4));
  };
  auto rdB = [&](const int8_t* lb, int j, int ks) {
    return *(const v4i*)(lb + 32768 + (wn + j * 32 + lrow) * 128 + (((ks * 2 + half) ^ x7) << 4));
  };

  v4i aR[2][4], bR[2][4];

  auto quad = [&](int mh, int nh) {
    __builtin_amdgcn_s_setprio(1);
#pragma unroll
    for (int ks = 0; ks < 4; ++ks) {
      acc[2 * mh + 0][nh] = __builtin_amdgcn_mfma_i32_32x32x32_i8(aR[0][ks], bR[nh][ks],
                                                                  acc[2 * mh + 0][nh], 0, 0, 0);
      acc[2 * mh + 1][nh] = __builtin_amdgcn_mfma_i32_32x32x32_i8(aR[1][ks], bR[nh][ks],
                                                                  acc[2 * mh + 1][nh], 0, 0, 0);
    }
    __builtin_amdgcn_s_setprio(0);
  };

  // prologue: tile0 fully + tile1 half0 (12 instrs); wait tile0 (8) landed
  stgHalf(0, lds0, 0);
  stgHalf(0, lds0, 1);
  stgHalf(128, lds1, 0);
  asm volatile("s_waitcnt vmcnt(4)" ::: "memory");
  __builtin_amdgcn_sched_barrier(0);
  __builtin_amdgcn_s_barrier();

#pragma unroll 1
  for (int it = 0; it < NI; ++it) {
    const bool nl = (it < NI - 1);
    const size_t ko = (size_t)it * 256;  // t0 byte-offset along K
    // ---------- tile t0 (lds0) ----------
    // ph0: quadrant (0,0); stage t1 half1
#pragma unroll
    for (int ks = 0; ks < 4; ++ks) {
      aR[0][ks] = rdA(lds0, 0, ks);
      aR[1][ks] = rdA(lds0, 1, ks);
      bR[0][ks] = rdB(lds0, 0, ks);
    }
    stgHalf(ko + 128, lds1, 1);
    __builtin_amdgcn_s_barrier();
    quad(0, 0);
    __builtin_amdgcn_s_barrier();
    // ph1: quadrant (0,1)
#pragma unroll
    for (int ks = 0; ks < 4; ++ks) bR[1][ks] = rdB(lds0, 1, ks);
    __builtin_amdgcn_s_barrier();
    quad(0, 1);
    __builtin_amdgcn_s_barrier();
    // ph2: quadrant (1,0)
#pragma unroll
    for (int ks = 0; ks < 4; ++ks) {
      aR[0][ks] = rdA(lds0, 2, ks);
      aR[1][ks] = rdA(lds0, 3, ks);
    }
    __builtin_amdgcn_s_barrier();
    quad(1, 0);
    __builtin_amdgcn_s_barrier();
    // ph3: quadrant (1,1); stage t0+2 half0; guard buf1 (t1) staged
    if (nl) stgHalf(ko + 256, lds0, 0);
    __builtin_amdgcn_s_barrier();
    quad(1, 1);
    if (nl) {
      asm volatile("s_waitcnt vmcnt(4)" ::: "memory");
    } else {
      asm volatile("s_waitcnt vmcnt(0)" ::: "memory");
    }
    __builtin_amdgcn_sched_barrier(0);
    __builtin_amdgcn_s_barrier();
    // ---------- tile t1 (lds1) ----------
    // ph4: quadrant (0,0); stage t0+2 half1
#pragma unroll
    for (int ks = 0; ks < 4; ++ks) {
      aR[0][ks] = rdA(lds1, 0, ks);
      aR[1][ks] = rdA(lds1, 1, ks);
      bR[0][ks] = rdB(lds1, 0, ks);
    }
    if (nl) stgHalf(ko + 256, lds0, 1);
    __builtin_amdgcn_s_barrier();
    quad(0, 0);
    __builtin_amdgcn_s_barrier();
    // ph5: quadrant (0,1)
#pragma unroll
    for (int ks = 0; ks < 4; ++ks) bR[1][ks] = rdB(lds1, 1, ks);
    __builtin_amdgcn_s_barrier();
    quad(0, 1);
    __builtin_amdgcn_s_barrier();
    // ph6: quadrant (1,0)
#pragma unroll
    for (int ks = 0; ks < 4; ++ks) {
      aR[0][ks] = rdA(lds1, 2, ks);
      aR[1][ks] = rdA(lds1, 3, ks);
    }
    __builtin_amdgcn_s_barrier();
    quad(1, 0);
    __builtin_amdgcn_s_barrier();
    // ph7: quadrant (1,1); stage t1+2 half0; guard buf0 (t0+2) staged
    if (nl) stgHalf(ko + 384, lds1, 0);
    __builtin_amdgcn_s_barrier();
    quad(1, 1);
    if (nl) {
      asm volatile("s_waitcnt vmcnt(4)" ::: "memory");
      __builtin_amdgcn_sched_barrier(0);
    }
    __builtin_amdgcn_s_barrier();
  }
}

// ---------------- GEMM1: C=xq@w1q^T, dequant+bias+swish -> bf16 h ----------------
__global__ __launch_bounds__(512, 2) void gemm1_kernel(const int8_t* __restrict__ Aq,
                                                       const int8_t* __restrict__ Bq,
                                                       const float* __restrict__ xscale,
                                                       const float* __restrict__ scal,
                                                       const float* __restrict__ bias,
                                                       ushort* __restrict__ H) {
  __shared__ __align__(16) int8_t smem[2 * 65536];  // 128 KB
  // XCD map: xcd = bid&7 owns m-tiles [xcd*8, xcd*8+8), sweeping all 16 n
  // per m-tile -> per-XCD hot set = w1q (4MB, == L2) + 1 A-tile (256KB).
  const int bid = blockIdx.x;          // 1024 blocks
  const int loc = bid >> 3;            // 0..127
  const int nIdx = loc & 15;           // 16 n-tiles
  const int mIdx = (bid & 7) * 8 + (loc >> 4);  // 64 m-tiles
  v16i acc[4][2] = {};
  gemm_core_r8<1024>(Aq, Bq, smem, acc, mIdx, nIdx);
  const float sw1 = scal[2];
  const int lane = threadIdx.x & 63;
  const int wave = threadIdx.x >> 6;
  const int m0 = mIdx * 256 + (wave & 1) * 128;
  const int n0 = nIdx * 256 + (wave >> 1) * 64;
  const int cn = lane & 31;
  const int h4 = (lane >> 5) << 2;
#pragma unroll
  for (int i = 0; i < 4; ++i) {
#pragma unroll
    for (int reg = 0; reg < 16; ++reg) {
      const int row = (reg & 3) + ((reg >> 2) << 3) + h4;  // C/D layout (m74/m101)
      const int m = m0 + i * 32 + row;
      const float rcp = 1.0f / (xscale[m] * sw1);
#pragma unroll
      for (int j = 0; j < 2; ++j) {
        const int n = n0 + j * 32 + cn;
        const float v = (float)acc[i][j][reg] * rcp + bias[n];
        const float hsw = v / (1.0f + __expf(-v));  // swish
        __hip_bfloat16 hb = __float2bfloat16(hsw);
        H[(size_t)m * 4096 + n] = *(const ushort*)&hb;
      }
    }
  }
}

// ---------------- GEMM2: C=hq@w2q^T, dequant+bias+mask+residual -> fp32 out ----------------
__global__ __launch_bounds__(512, 2) void gemm2_kernel(const int8_t* __restrict__ Aq,
                                                       const int8_t* __restrict__ Bq,
                                                       const float* __restrict__ hscale,
                                                       const float* __restrict__ scal,
                                                       const float* __restrict__ bias,
                                                       const float* __restrict__ x,
                                                       const float* __restrict__ mask,
                                                       float* __restrict__ out) {
  __shared__ __align__(16) int8_t smem[2 * 65536];  // 128 KB
  const int bid = blockIdx.x;          // 256 blocks
  const int loc = bid >> 3;            // 0..31
  const int nIdx = loc & 3;            // 4 n-tiles
  const int mIdx = (bid & 7) * 8 + (loc >> 2);  // 64 m-tiles
  v16i acc[4][2] = {};
  gemm_core_r8<4096>(Aq, Bq, smem, acc, mIdx, nIdx);
  const float sw2 = scal[3];
  const int lane = threadIdx.x & 63;
  const int wave = threadIdx.x >> 6;
  const int m0 = mIdx * 256 + (wave & 1) * 128;
  const int n0 = nIdx * 256 + (wave >> 1) * 64;
  const int cn = lane & 31;
  const int h4 = (lane >> 5) << 2;
#pragma unroll
  for (int i = 0; i < 4; ++i) {
#pragma unroll
    for (int reg = 0; reg < 16; ++reg) {
      const int row = (reg & 3) + ((reg >> 2) << 3) + h4;
      const int m = m0 + i * 32 + row;
      const float rcp = 1.0f / (hscale[m] * sw2);
      const float mk = 0.5f * mask[m];
#pragma unroll
      for (int j = 0; j < 2; ++j) {
        const int n = n0 + j * 32 + cn;
        const float v = (float)acc[i][j][reg] * rcp + bias[n];
        const size_t idx = (size_t)m * 1024 + n;
        out[idx] = x[idx] + mk * v;
      }
    }
  }
}

extern "C" void kernel_launch(void* const* d_in, const int* in_sizes, int n_in, void* d_out,
                              int out_size, void* d_ws, size_t ws_size, hipStream_t stream) {
  const float* x = (const float*)d_in[0];      // [8,2048,1024]
  const float* mask = (const float*)d_in[1];   // [8,2048,1]
  const float* gamma = (const float*)d_in[2];  // [1024]
  const float* beta = (const float*)d_in[3];   // [1024]
  const float* w1 = (const float*)d_in[4];     // [4096,1024]
  const float* b1 = (const float*)d_in[5];     // [4096]
  const float* w2 = (const float*)d_in[6];     // [1024,4096]
  const float* b2 = (const float*)d_in[7];     // [1024]
  const int* bits = (const int*)d_in[8];       // scalar
  float* out = (float*)d_out;

  char* ws = (char*)d_ws;
  int* wmax = (int*)ws;                              // slots [0],[1]
  float* scal = (float*)ws;                          // [2]=sw1 [3]=sw2 [4]=qb
  float* xscale = (float*)(ws + (1u << 20));         // 16384 f32
  float* hscale = (float*)(ws + (2u << 20));         // 16384 f32
  int8_t* w1q = (int8_t*)(ws + (4u << 20));          // 4 MB
  int8_t* w2q = (int8_t*)(ws + (8u << 20));          // 4 MB
  int8_t* xq = (int8_t*)(ws + (12u << 20));          // 16 MB
  int8_t* hq = (int8_t*)(ws + (28u << 20));          // 64 MB
  ushort* h = (ushort*)(ws + (size_t)(92u << 20));   // 128 MB bf16

  const int NW = 4096 * 1024;  // elements per weight matrix

  absmax_kernel<<<1024, 256, 0, stream>>>(w1, NW / 4, wmax + 0);
  absmax_kernel<<<1024, 256, 0, stream>>>(w2, NW / 4, wmax + 1);
  scales_kernel<<<1, 1, 0, stream>>>(wmax, bits, scal);
  wquant_kernel<<<NW / 1024, 256, 0, stream>>>(w1, scal, 0, w1q);
  wquant_kernel<<<NW / 1024, 256, 0, stream>>>(w2, scal, 1, w2q);
  ln_quant_kernel<<<16384, 256, 0, stream>>>(x, gamma, beta, xq, xscale);
  gemm1_kernel<<<1024, 512, 0, stream>>>(xq, w1q, xscale, scal, b1, h);
  hquant_kernel<<<16384, 256, 0, stream>>>(h, hq, hscale);
  gemm2_kernel<<<256, 512, 0, stream>>>(hq, w2q, hscale, scal, b2, x, mask, out);
}

// Round 5
// 418.500 us; speedup vs baseline: 1.0213x; 1.0213x over previous
//
#include <hip/hip_runtime.h>
#include <hip/hip_bf16.h>
#include <stdint.h>

// BitNet-style quantized FFN for MI355X (gfx950).
// Pipeline: absmax(w1,w2) -> scales -> wquant -> LN+actquant ->
//           i8 GEMM1 (+dequant+bias+swish, bf16 out) -> actquant(h) ->
//           i8 GEMM2 (+dequant+bias+mask+residual, fp32 out)
// R9: consolidation. R5-R8 (ring-3 counted vmcnt, reg-dbuf, 8-phase) all
//     landed 19-24% MfmaUtil == R4 -> schedule is not the limiter; LDS-read
//     pipe work ~= MFMA work for this i8 geometry, overlap quality decides.
//     Revert to the R4 core (verified best, 124us gemm1) with ONE lever:
//     __launch_bounds__(256,3) -> 3 resident blocks/CU (48KB LDS x3 = 144
//     <= 160KB) for cross-block pipe overlap (m114 mechanism, the only one
//     that measurably helped: R4 2-block > R7 1-block).
//     Aux: ln_quant/hquant wave-per-row (no LDS, no syncthreads).
// NB: SQ_LDS_BANK_CONFLICT == 8 cyc x staging-instr count (artifact of
//     global_load_lds write occupancy), not read conflicts.

typedef int v4i __attribute__((ext_vector_type(4)));
typedef int v16i __attribute__((ext_vector_type(16)));

#define BK 128   // bytes (=i8 elems) of K per tile

__device__ __forceinline__ float wave_max64(float v) {
#pragma unroll
  for (int off = 32; off; off >>= 1) v = fmaxf(v, __shfl_xor(v, off, 64));
  return v;
}

__device__ __forceinline__ void load16_to_lds(const int8_t* g, int8_t* l) {
  __builtin_amdgcn_global_load_lds((const __attribute__((address_space(1))) void*)g,
                                   (__attribute__((address_space(3))) void*)l, 16, 0, 0);
}

// ---------------- per-tensor weight absmax ----------------
__global__ __launch_bounds__(256) void absmax_kernel(const float* __restrict__ w, int n4,
                                                     int* __restrict__ slot) {
  float m = 0.f;
  const float4* w4 = (const float4*)w;
  for (int i = blockIdx.x * 256 + threadIdx.x; i < n4; i += gridDim.x * 256) {
    float4 v = w4[i];
    m = fmaxf(fmaxf(fabsf(v.x), fabsf(v.y)), fmaxf(fmaxf(fabsf(v.z), fabsf(v.w)), m));
  }
  m = wave_max64(m);
  __shared__ float sm[4];
  int lane = threadIdx.x & 63, wv = threadIdx.x >> 6;
  if (!lane) sm[wv] = m;
  __syncthreads();
  if (!threadIdx.x) {
    m = fmaxf(fmaxf(sm[0], sm[1]), fmaxf(sm[2], sm[3]));
    atomicMax(slot, __float_as_int(m));  // nonneg float bits are int-monotone
  }
}

// ---------------- scales ----------------
__global__ void scales_kernel(const int* __restrict__ wmax, const int* __restrict__ bits,
                              float* __restrict__ scal) {
  float qb = (float)((1 << (bits[0] - 1)) - 1);
  scal[2] = qb / fmaxf(__int_as_float(wmax[0]), 1e-5f);
  scal[3] = qb / fmaxf(__int_as_float(wmax[1]), 1e-5f);
  scal[4] = qb;
}

// ---------------- weight quantization to int8 ----------------
__global__ __launch_bounds__(256) void wquant_kernel(const float* __restrict__ w,
                                                     const float* __restrict__ scal, int which,
                                                     int8_t* __restrict__ out) {
  float s = scal[2 + which], qb = scal[4];
  int i = blockIdx.x * 256 + threadIdx.x;
  float4 v = ((const float4*)w)[i];
  char4 q;
  q.x = (char)(int)rintf(fminf(fmaxf(v.x * s, -qb), qb));
  q.y = (char)(int)rintf(fminf(fmaxf(v.y * s, -qb), qb));
  q.z = (char)(int)rintf(fminf(fmaxf(v.z * s, -qb), qb));
  q.w = (char)(int)rintf(fminf(fmaxf(v.w * s, -qb), qb));
  ((char4*)out)[i] = q;
}

// ---------------- fused LayerNorm + per-row int8 absmax quant ----------------
// wave-per-row: 4 waves/block, each wave owns one row (D=1024, 16 f32/lane).
// No LDS, no __syncthreads -- pure 64-lane shfl reduction.
__global__ __launch_bounds__(256) void ln_quant_kernel(const float* __restrict__ x,
                                                       const float* __restrict__ gamma,
                                                       const float* __restrict__ beta,
                                                       int8_t* __restrict__ xq,
                                                       float* __restrict__ xscale) {
  const int wv = threadIdx.x >> 6;
  const int lane = threadIdx.x & 63;
  const int row = blockIdx.x * 4 + wv;
  const float4* xr = (const float4*)(x + (size_t)row * 1024);
  float4 v[4];
#pragma unroll
  for (int k = 0; k < 4; ++k) v[k] = xr[lane + k * 64];
  float s = 0.f, ss = 0.f;
#pragma unroll
  for (int k = 0; k < 4; ++k) {
    s += v[k].x + v[k].y + v[k].z + v[k].w;
    ss = fmaf(v[k].x, v[k].x, fmaf(v[k].y, v[k].y, fmaf(v[k].z, v[k].z, fmaf(v[k].w, v[k].w, ss))));
  }
#pragma unroll
  for (int off = 32; off; off >>= 1) {
    s += __shfl_xor(s, off, 64);
    ss += __shfl_xor(ss, off, 64);
  }
  const float mu = s * (1.f / 1024.f);
  const float var = ss * (1.f / 1024.f) - mu * mu;
  const float rstd = rsqrtf(var + 1e-5f);
  const float4* g4 = (const float4*)gamma;
  const float4* b4 = (const float4*)beta;
  float am = 0.f;
#pragma unroll
  for (int k = 0; k < 4; ++k) {
    const float4 g = g4[lane + k * 64];
    const float4 b = b4[lane + k * 64];
    v[k].x = (v[k].x - mu) * rstd * g.x + b.x;
    v[k].y = (v[k].y - mu) * rstd * g.y + b.y;
    v[k].z = (v[k].z - mu) * rstd * g.z + b.z;
    v[k].w = (v[k].w - mu) * rstd * g.w + b.w;
    am = fmaxf(am, fmaxf(fmaxf(fabsf(v[k].x), fabsf(v[k].y)), fmaxf(fabsf(v[k].z), fabsf(v[k].w))));
  }
  am = wave_max64(am);
  const float scale = 127.f / fmaxf(am, 1e-5f);
  char4* qr = (char4*)(xq + (size_t)row * 1024);
#pragma unroll
  for (int k = 0; k < 4; ++k) {
    char4 q;
    q.x = (char)(int)rintf(fminf(fmaxf(v[k].x * scale, -127.f), 127.f));
    q.y = (char)(int)rintf(fminf(fmaxf(v[k].y * scale, -127.f), 127.f));
    q.z = (char)(int)rintf(fminf(fmaxf(v[k].z * scale, -127.f), 127.f));
    q.w = (char)(int)rintf(fminf(fmaxf(v[k].w * scale, -127.f), 127.f));
    qr[lane + k * 64] = q;
  }
  if (!lane) xscale[row] = scale;
}

// ---------------- per-row int8 absmax quant of bf16 h [16384,4096] ----------------
// wave-per-row: 4 waves/block, one row per wave (64 bf16/lane), shfl-only reduce.
__global__ __launch_bounds__(256) void hquant_kernel(const ushort* __restrict__ h,
                                                     int8_t* __restrict__ hq,
                                                     float* __restrict__ hscale) {
  const int wv = threadIdx.x >> 6;
  const int lane = threadIdx.x & 63;
  const int row = blockIdx.x * 4 + wv;
  const int4* p = (const int4*)(h + (size_t)row * 4096);
  float f[64];
#pragma unroll
  for (int k = 0; k < 8; ++k) {
    union { int4 i4; ushort u[8]; } ua;
    ua.i4 = p[lane + k * 64];
#pragma unroll
    for (int i = 0; i < 8; ++i) f[k * 8 + i] = __uint_as_float((unsigned)ua.u[i] << 16);
  }
  float am = 0.f;
#pragma unroll
  for (int i = 0; i < 64; ++i) am = fmaxf(am, fabsf(f[i]));
  am = wave_max64(am);
  const float scale = 127.f / fmaxf(am, 1e-5f);
  int2* qr = (int2*)(hq + (size_t)row * 4096);
#pragma unroll
  for (int k = 0; k < 8; ++k) {
    union { int2 i2; char c[8]; } q;
#pragma unroll
    for (int i = 0; i < 8; ++i)
      q.c[i] = (char)(int)rintf(fminf(fmaxf(f[k * 8 + i] * scale, -127.f), 127.f));
    qr[lane + k * 64] = q.i2;
  }
  if (!lane) hscale[row] = scale;
}

// ---------------- i8 MFMA GEMM core ----------------
// Block tile BMt x BNt, BK=128 B. 4 waves tiled 2x2, wave tile (BMt/2)x(BNt/2),
// per-wave frags AM x AN of 32x32x32 (AM=BMt/64, AN=BNt/64).
// LDS: 128-B rows, k-chunk s of row r stored at physical slot s^(r&7)
// (swizzle applied at global-fetch addressing; global_load_lds dest is
// wave-uniform base + lane*16).
template <int K, int BMt, int BNt>
__device__ __forceinline__ void gemm_core(const int8_t* __restrict__ A,
                                          const int8_t* __restrict__ B, int8_t* As, int8_t* Bs,
                                          v16i (&acc)[BMt / 64][BNt / 64]) {
  constexpr int AM = BMt / 64, AN = BNt / 64;
  const int tid = threadIdx.x;
  const int lane = tid & 63;
  const int wave = tid >> 6;
  const int wm = (wave & 1) * (BMt / 2);
  const int wn = (wave >> 1) * (BNt / 2);
  const int lrow = lane & 31;
  const int half = lane >> 5;
  const int x7 = lrow & 7;
  const size_t m0 = (size_t)blockIdx.y * BMt;
  const size_t n0 = (size_t)blockIdx.x * BNt;

  // staging: thread handles chunk (tid + t*256); row r = tid>>3 (+32 per t,
  // preserves r&7), swizzled k-offset cs
  const int r = tid >> 3;
  const int cs = ((tid & 7) ^ (r & 7)) << 4;
  const int8_t* ga = A + (m0 + r) * K + cs;
  const int8_t* gb = B + (n0 + r) * K + cs;
  int8_t* la = As + tid * 16;
  int8_t* lb = Bs + tid * 16;

  for (int k0 = 0; k0 < K; k0 += BK) {
    __syncthreads();
#pragma unroll
    for (int t = 0; t < BMt / 32; ++t)
      load16_to_lds(ga + (size_t)(t * 32) * K + k0, la + t * 4096);
#pragma unroll
    for (int t = 0; t < BNt / 32; ++t)
      load16_to_lds(gb + (size_t)(t * 32) * K + k0, lb + t * 4096);
    __syncthreads();
#pragma unroll
    for (int ks = 0; ks < 4; ++ks) {
      const int so = ((ks * 2 + half) ^ x7) << 4;
      v4i af[AM], bf[AN];
#pragma unroll
      for (int i = 0; i < AM; ++i)
        af[i] = *(const v4i*)(As + (wm + i * 32 + lrow) * 128 + so);
#pragma unroll
      for (int j = 0; j < AN; ++j)
        bf[j] = *(const v4i*)(Bs + (wn + j * 32 + lrow) * 128 + so);
#pragma unroll
      for (int i = 0; i < AM; ++i)
#pragma unroll
        for (int j = 0; j < AN; ++j)
          acc[i][j] = __builtin_amdgcn_mfma_i32_32x32x32_i8(af[i], bf[j], acc[i][j], 0, 0, 0);
    }
  }
}

// ---------------- GEMM1: C=xq@w1q^T, dequant+bias+swish -> bf16 h ----------------
// 128x256 tile: As 16KB, Bs 32KB; 3 resident blocks/CU (144KB LDS)
__global__ __launch_bounds__(256, 3) void gemm1_kernel(const int8_t* __restrict__ Aq,
                                                       const int8_t* __restrict__ Bq,
                                                       const float* __restrict__ xscale,
                                                       const float* __restrict__ scal,
                                                       const float* __restrict__ bias,
                                                       ushort* __restrict__ H) {
  __shared__ __align__(16) int8_t As[128 * 128];
  __shared__ __align__(16) int8_t Bs[256 * 128];
  v16i acc[2][4] = {};
  gemm_core<1024, 128, 256>(Aq, Bq, As, Bs, acc);
  const float sw1 = scal[2];
  const int lane = threadIdx.x & 63;
  const int wave = threadIdx.x >> 6;
  const int m0 = blockIdx.y * 128 + (wave & 1) * 64;
  const int n0 = blockIdx.x * 256 + (wave >> 1) * 128;
  const int cn = lane & 31;
  const int h4 = (lane >> 5) << 2;
#pragma unroll
  for (int i = 0; i < 2; ++i) {
#pragma unroll
    for (int reg = 0; reg < 16; ++reg) {
      const int row = (reg & 3) + ((reg >> 2) << 3) + h4;  // C/D layout (m74/m101)
      const int m = m0 + i * 32 + row;
      const float rcp = 1.0f / (xscale[m] * sw1);
#pragma unroll
      for (int j = 0; j < 4; ++j) {
        const int n = n0 + j * 32 + cn;
        const float v = (float)acc[i][j][reg] * rcp + bias[n];
        const float hsw = v / (1.0f + __expf(-v));  // swish
        __hip_bfloat16 hb = __float2bfloat16(hsw);
        H[(size_t)m * 4096 + n] = *(const ushort*)&hb;
      }
    }
  }
}

// ---------------- GEMM2: C=hq@w2q^T, dequant+bias+mask+residual -> fp32 out ----------------
// 256x128 tile: As 32KB, Bs 16KB; 3 resident blocks/CU
__global__ __launch_bounds__(256, 3) void gemm2_kernel(const int8_t* __restrict__ Aq,
                                                       const int8_t* __restrict__ Bq,
                                                       const float* __restrict__ hscale,
                                                       const float* __restrict__ scal,
                                                       const float* __restrict__ bias,
                                                       const float* __restrict__ x,
                                                       const float* __restrict__ mask,
                                                       float* __restrict__ out) {
  __shared__ __align__(16) int8_t As[256 * 128];
  __shared__ __align__(16) int8_t Bs[128 * 128];
  v16i acc[4][2] = {};
  gemm_core<4096, 256, 128>(Aq, Bq, As, Bs, acc);
  const float sw2 = scal[3];
  const int lane = threadIdx.x & 63;
  const int wave = threadIdx.x >> 6;
  const int m0 = blockIdx.y * 256 + (wave & 1) * 128;
  const int n0 = blockIdx.x * 128 + (wave >> 1) * 64;
  const int cn = lane & 31;
  const int h4 = (lane >> 5) << 2;
#pragma unroll
  for (int i = 0; i < 4; ++i) {
#pragma unroll
    for (int reg = 0; reg < 16; ++reg) {
      const int row = (reg & 3) + ((reg >> 2) << 3) + h4;
      const int m = m0 + i * 32 + row;
      const float rcp = 1.0f / (hscale[m] * sw2);
      const float mk = 0.5f * mask[m];
#pragma unroll
      for (int j = 0; j < 2; ++j) {
        const int n = n0 + j * 32 + cn;
        const float v = (float)acc[i][j][reg] * rcp + bias[n];
        const size_t idx = (size_t)m * 1024 + n;
        out[idx] = x[idx] + mk * v;
      }
    }
  }
}

extern "C" void kernel_launch(void* const* d_in, const int* in_sizes, int n_in, void* d_out,
                              int out_size, void* d_ws, size_t ws_size, hipStream_t stream) {
  const float* x = (const float*)d_in[0];      // [8,2048,1024]
  const float* mask = (const float*)d_in[1];   // [8,2048,1]
  const float* gamma = (const float*)d_in[2];  // [1024]
  const float* beta = (const float*)d_in[3];   // [1024]
  const float* w1 = (const float*)d_in[4];     // [4096,1024]
  const float* b1 = (const float*)d_in[5];     // [4096]
  const float* w2 = (const float*)d_in[6];     // [1024,4096]
  const float* b2 = (const float*)d_in[7];     // [1024]
  const int* bits = (const int*)d_in[8];       // scalar
  float* out = (float*)d_out;

  char* ws = (char*)d_ws;
  int* wmax = (int*)ws;                              // slots [0],[1]
  float* scal = (float*)ws;                          // [2]=sw1 [3]=sw2 [4]=qb
  float* xscale = (float*)(ws + (1u << 20));         // 16384 f32
  float* hscale = (float*)(ws + (2u << 20));         // 16384 f32
  int8_t* w1q = (int8_t*)(ws + (4u << 20));          // 4 MB
  int8_t* w2q = (int8_t*)(ws + (8u << 20));          // 4 MB
  int8_t* xq = (int8_t*)(ws + (12u << 20));          // 16 MB
  int8_t* hq = (int8_t*)(ws + (28u << 20));          // 64 MB
  ushort* h = (ushort*)(ws + (size_t)(92u << 20));   // 128 MB bf16

  const int NW = 4096 * 1024;  // elements per weight matrix

  absmax_kernel<<<1024, 256, 0, stream>>>(w1, NW / 4, wmax + 0);
  absmax_kernel<<<1024, 256, 0, stream>>>(w2, NW / 4, wmax + 1);
  scales_kernel<<<1, 1, 0, stream>>>(wmax, bits, scal);
  wquant_kernel<<<NW / 1024, 256, 0, stream>>>(w1, scal, 0, w1q);
  wquant_kernel<<<NW / 1024, 256, 0, stream>>>(w2, scal, 1, w2q);
  ln_quant_kernel<<<4096, 256, 0, stream>>>(x, gamma, beta, xq, xscale);
  gemm1_kernel<<<dim3(4096 / 256, 16384 / 128), 256, 0, stream>>>(xq, w1q, xscale, scal, b1, h);
  hquant_kernel<<<4096, 256, 0, stream>>>(h, hq, hscale);
  gemm2_kernel<<<dim3(1024 / 128, 16384 / 256), 256, 0, stream>>>(hq, w2q, hscale, scal, b2, x,
                                                                  mask, out);
}